// Round 2
// baseline (689.540 us; speedup 1.0000x reference)
//
#include <hip/hip_runtime.h>
#include <stdint.h>

#define TPB 256
#define RPT 4
#define NL 4

typedef _Float16 half2v __attribute__((ext_vector_type(2)));

static __device__ __forceinline__ uint32_t packh2(float a, float b) {
  half2v h;
  h.x = (_Float16)a;
  h.y = (_Float16)b;
  return __builtin_bit_cast(uint32_t, h);
}
static __device__ __forceinline__ float2 unpackh2(uint32_t u) {
  half2v h = __builtin_bit_cast(half2v, u);
  return make_float2((float)h.x, (float)h.y);
}
static __device__ __forceinline__ float fdot2h(uint32_t a, uint32_t b, float c) {
  return __builtin_amdgcn_fdot2(__builtin_bit_cast(half2v, a),
                                __builtin_bit_cast(half2v, b), c, false);
}

// wpk1[l][o][dp]  = half2(W1[l][o][2dp], W1[l][o][2dp+1])   o-major   (8192 u32)
// wpk2[l][dhp][o] = half2(W2[l][o][2dhp], W2[l][o][2dhp+1]) dhp-major (8192 u32)
__global__ void pack_weights_kernel(const float* __restrict__ ff1_w,
                                    const float* __restrict__ ff2_w,
                                    uint32_t* __restrict__ wpk1,
                                    uint32_t* __restrict__ wpk2) {
  int idx = blockIdx.x * blockDim.x + threadIdx.x;
  if (idx < 8192) {
    int l = idx >> 11, o = (idx >> 5) & 63, dp = idx & 31;
    wpk1[idx] = packh2(ff1_w[(l * 64 + o) * 64 + 2 * dp],
                       ff1_w[(l * 64 + o) * 64 + 2 * dp + 1]);
  } else if (idx < 16384) {
    int j = idx - 8192;
    int l = j >> 11, dhp = (j >> 6) & 31, o = j & 63;
    wpk2[j] = packh2(ff2_w[(l * 64 + o) * 64 + 2 * dhp],
                     ff2_w[(l * 64 + o) * 64 + 2 * dhp + 1]);
  }
}

// Butterfly stage with literal m: all v[] indices compile-time constant.
#define BSTAGE(m)                                                     \
  do {                                                                \
    _Pragma("unroll") for (int k = 0; k < (m); k++) {                 \
      bool up = (lane & (m)) != 0;                                    \
      float send = up ? v[k] : v[k + (m)];                            \
      float keep = up ? v[k + (m)] : v[k];                            \
      v[k] = keep + __shfl_xor(send, (m), 64);                        \
    }                                                                 \
  } while (0)

__global__ __launch_bounds__(TPB, 2) void aat_kernel(
    const int* __restrict__ tokens, const float* __restrict__ emb,
    const float* __restrict__ lin_w, const float* __restrict__ lin_b,
    const float* __restrict__ ff1_b, const float* __restrict__ ff2_b,
    const float* __restrict__ n1_g, const float* __restrict__ n1_b,
    const float* __restrict__ n2_g, const float* __restrict__ n2_b,
    const float* __restrict__ out_w, const float* __restrict__ out_b,
    const uint32_t* __restrict__ wpk1, const uint32_t* __restrict__ wpk2,
    float* __restrict__ out) {
  __shared__ float red4[4][64];
  __shared__ float avgbuf[64];
  __shared__ __align__(8) float attnbuf[64];

  const int t = threadIdx.x;
  const int b = blockIdx.x;
  const int lane = t & 63;
  const int wv = t >> 6;

  uint32_t xpk[RPT][32];  // x rows, packed f16 pairs, register-resident

  // ---------------- embed * sqrt(d) + positional encoding ----------------
  #pragma unroll
  for (int r = 0; r < RPT; r++) {
    int s = t + r * TPB;
    if (s < 1000) {
      int tok = tokens[b * 1000 + s];
      const float4* ev = (const float4*)(emb + (size_t)tok * 64);
      #pragma unroll
      for (int q = 0; q < 16; q++) {
        float4 v4 = ev[q];
        float xv[4] = {v4.x, v4.y, v4.z, v4.w};
        #pragma unroll
        for (int j = 0; j < 4; j++) {
          int d = 4 * q + j;
          // div_i = 10000^(-i/32); log2(10000)/32 = 0.41524101186
          float div = exp2f(-0.4152410118609203f * (float)(d >> 1));
          float ang = (float)s * div;
          float pe = (d & 1) ? cosf(ang) : sinf(ang);
          xv[j] = xv[j] * 8.0f + pe;
        }
        xpk[r][2 * q] = packh2(xv[0], xv[1]);
        xpk[r][2 * q + 1] = packh2(xv[2], xv[3]);
      }
    } else {
      #pragma unroll
      for (int dp = 0; dp < 32; dp++) xpk[r][dp] = 0u;
    }
  }

  for (int l = 0; l < NL; l++) {
    // ---------------- avg over sequence: butterfly reduce ----------------
    {
      float v[64];
      #pragma unroll
      for (int dp = 0; dp < 32; dp++) {
        float s0 = 0.f, s1 = 0.f;
        #pragma unroll
        for (int r = 0; r < RPT; r++) {
          if (t + r * TPB < 1000) {
            float2 xv = unpackh2(xpk[r][dp]);
            s0 += xv.x;
            s1 += xv.y;
          }
        }
        v[2 * dp] = s0;
        v[2 * dp + 1] = s1;
      }
      BSTAGE(32); BSTAGE(16); BSTAGE(8); BSTAGE(4); BSTAGE(2); BSTAGE(1);
      __syncthreads();
      red4[wv][lane] = v[0];
    }
    __syncthreads();
    if (t < 64)
      avgbuf[t] = (red4[0][t] + red4[1][t] + red4[2][t] + red4[3][t]) * 1e-3f;
    __syncthreads();
    if (t < 64) {  // attn[o] = lin_b[o] + sum_d avg[d]*lin_w[o][d]
      const float* wr = lin_w + (size_t)(l * 64 + t) * 64;
      float a0 = lin_b[l * 64 + t], a1 = 0.f, a2 = 0.f, a3 = 0.f;
      #pragma unroll
      for (int d = 0; d < 64; d += 4) {
        a0 += avgbuf[d] * wr[d];
        a1 += avgbuf[d + 1] * wr[d + 1];
        a2 += avgbuf[d + 2] * wr[d + 2];
        a3 += avgbuf[d + 3] * wr[d + 3];
      }
      attnbuf[t] = (a0 + a1) + (a2 + a3);
    }
    __syncthreads();

    // ---------------- per-row: LN1 -> fused FF -> LN2 (all static idx) ----
    #pragma unroll
    for (int r = 0; r < RPT; r++) {
      // LN1 stats over a = x + attn; store a in place (f16)
      float m0 = 0.f, m1 = 0.f, q0 = 0.f, q1 = 0.f;
      #pragma unroll
      for (int dp = 0; dp < 32; dp++) {
        float2 xv = unpackh2(xpk[r][dp]);
        float2 at = ((const float2*)attnbuf)[dp];
        float a0 = xv.x + at.x, a1 = xv.y + at.y;
        m0 += a0;
        m1 += a1;
        q0 = fmaf(a0, a0, q0);
        q1 = fmaf(a1, a1, q1);
        xpk[r][dp] = packh2(a0, a1);
      }
      float mu = (m0 + m1) * (1.0f / 64.0f);
      float var = (q0 + q1) * (1.0f / 64.0f) - mu * mu;
      float rs = rsqrtf(var + 1e-5f);
      #pragma unroll
      for (int dp = 0; dp < 32; dp++) {
        float2 av = unpackh2(xpk[r][dp]);
        float y0 = fmaf((av.x - mu) * rs, n1_g[l * 64 + 2 * dp], n1_b[l * 64 + 2 * dp]);
        float y1 = fmaf((av.y - mu) * rs, n1_g[l * 64 + 2 * dp + 1], n1_b[l * 64 + 2 * dp + 1]);
        xpk[r][dp] = packh2(y0, y1);  // y = LN1 out (residual for LN2)
      }

      // fused mm1 -> relu -> mm2 partial accumulation
      float acc2[64];
      #pragma unroll
      for (int o = 0; o < 64; o++) acc2[o] = ff2_b[l * 64 + o];

      #pragma unroll 1
      for (int og = 0; og < 16; og++) {   // rolled: no register array indexed by og
        const uint32_t* wb1 = wpk1 + (size_t)(l * 64 + og * 4) * 32;
        float a0 = ff1_b[l * 64 + og * 4 + 0];
        float a1 = ff1_b[l * 64 + og * 4 + 1];
        float a2 = ff1_b[l * 64 + og * 4 + 2];
        float a3 = ff1_b[l * 64 + og * 4 + 3];
        #pragma unroll
        for (int dp = 0; dp < 32; dp++) {
          uint32_t y2 = xpk[r][dp];
          a0 = fdot2h(y2, wb1[dp], a0);
          a1 = fdot2h(y2, wb1[32 + dp], a1);
          a2 = fdot2h(y2, wb1[64 + dp], a2);
          a3 = fdot2h(y2, wb1[96 + dp], a3);
        }
        uint32_t h01 = packh2(fmaxf(a0, 0.f), fmaxf(a1, 0.f));
        uint32_t h23 = packh2(fmaxf(a2, 0.f), fmaxf(a3, 0.f));
        const uint32_t* wb2 = wpk2 + (size_t)l * 2048 + (size_t)(og * 2) * 64;
        #pragma unroll
        for (int o = 0; o < 64; o++)
          acc2[o] = fdot2h(h23, wb2[64 + o], fdot2h(h01, wb2[o], acc2[o]));
      }

      // residual + LN2 stats (static), store t in place
      float mm0 = 0.f, mm1v = 0.f, qq0 = 0.f, qq1 = 0.f;
      #pragma unroll
      for (int dp = 0; dp < 32; dp++) {
        float2 yv = unpackh2(xpk[r][dp]);
        float t0 = acc2[2 * dp] + yv.x;
        float t1 = acc2[2 * dp + 1] + yv.y;
        mm0 += t0;
        mm1v += t1;
        qq0 = fmaf(t0, t0, qq0);
        qq1 = fmaf(t1, t1, qq1);
        xpk[r][dp] = packh2(t0, t1);
      }
      mu = (mm0 + mm1v) * (1.0f / 64.0f);
      var = (qq0 + qq1) * (1.0f / 64.0f) - mu * mu;
      rs = rsqrtf(var + 1e-5f);
      #pragma unroll
      for (int dp = 0; dp < 32; dp++) {
        float2 tv = unpackh2(xpk[r][dp]);
        float x0 = fmaf((tv.x - mu) * rs, n2_g[l * 64 + 2 * dp], n2_b[l * 64 + 2 * dp]);
        float x1 = fmaf((tv.y - mu) * rs, n2_g[l * 64 + 2 * dp + 1], n2_b[l * 64 + 2 * dp + 1]);
        xpk[r][dp] = packh2(x0, x1);
      }
    }
  }

  // ---------------- output projection [B,S,2] ----------------
  #pragma unroll
  for (int r = 0; r < RPT; r++) {
    int s = t + r * TPB;
    if (s < 1000) {
      float a0 = out_b[0], a1 = out_b[1];
      #pragma unroll
      for (int dp = 0; dp < 32; dp++) {
        float2 xv = unpackh2(xpk[r][dp]);
        a0 += xv.x * out_w[2 * dp] + xv.y * out_w[2 * dp + 1];
        a1 += xv.x * out_w[64 + 2 * dp] + xv.y * out_w[64 + 2 * dp + 1];
      }
      float2 res;
      res.x = a0;
      res.y = a1;
      *(float2*)(out + (size_t)(b * 1000 + s) * 2) = res;
    }
  }
}

extern "C" void kernel_launch(void* const* d_in, const int* in_sizes, int n_in,
                              void* d_out, int out_size, void* d_ws, size_t ws_size,
                              hipStream_t stream) {
  const int* tokens = (const int*)d_in[0];
  const float* emb = (const float*)d_in[1];
  const float* lin_w = (const float*)d_in[2];
  const float* lin_b = (const float*)d_in[3];
  const float* ff1_w = (const float*)d_in[4];
  const float* ff1_b = (const float*)d_in[5];
  const float* ff2_w = (const float*)d_in[6];
  const float* ff2_b = (const float*)d_in[7];
  const float* n1_g = (const float*)d_in[8];
  const float* n1_b = (const float*)d_in[9];
  const float* n2_g = (const float*)d_in[10];
  const float* n2_b = (const float*)d_in[11];
  const float* out_w = (const float*)d_in[12];
  const float* out_b = (const float*)d_in[13];
  float* out = (float*)d_out;

  uint32_t* wpk1 = (uint32_t*)d_ws;       // 32 KiB
  uint32_t* wpk2 = wpk1 + 4 * 32 * 64;    // 32 KiB

  pack_weights_kernel<<<64, TPB, 0, stream>>>(ff1_w, ff2_w, wpk1, wpk2);
  aat_kernel<<<512, TPB, 0, stream>>>(tokens, emb, lin_w, lin_b, ff1_b, ff2_b,
                                      n1_g, n1_b, n2_g, n2_b, out_w, out_b,
                                      wpk1, wpk2, out);
}

// Round 3
// 656.798 us; speedup vs baseline: 1.0499x; 1.0499x over previous
//
#include <hip/hip_runtime.h>
#include <stdint.h>

#define TPB 512
#define NL 4

typedef _Float16 half2v __attribute__((ext_vector_type(2)));
typedef uint32_t u32v32 __attribute__((ext_vector_type(32)));
typedef float f32v32 __attribute__((ext_vector_type(32)));

static __device__ __forceinline__ uint32_t packh2(float a, float b) {
  half2v h;
  h.x = (_Float16)a;
  h.y = (_Float16)b;
  return __builtin_bit_cast(uint32_t, h);
}
static __device__ __forceinline__ float2 unpackh2(uint32_t u) {
  half2v h = __builtin_bit_cast(half2v, u);
  return make_float2((float)h.x, (float)h.y);
}
static __device__ __forceinline__ float fdot2h(uint32_t a, uint32_t b, float c) {
  return __builtin_amdgcn_fdot2(__builtin_bit_cast(half2v, a),
                                __builtin_bit_cast(half2v, b), c, false);
}

// wpk1[l][o][dp]  = half2(W1[l][o][2dp], W1[l][o][2dp+1])   o-major   (8192 u32)
// wpk2[l][dhp][o] = half2(W2[l][o][2dhp], W2[l][o][2dhp+1]) dhp-major (8192 u32)
__global__ void pack_weights_kernel(const float* __restrict__ ff1_w,
                                    const float* __restrict__ ff2_w,
                                    uint32_t* __restrict__ wpk1,
                                    uint32_t* __restrict__ wpk2) {
  int idx = blockIdx.x * blockDim.x + threadIdx.x;
  if (idx < 8192) {
    int l = idx >> 11, o = (idx >> 5) & 63, dp = idx & 31;
    wpk1[idx] = packh2(ff1_w[(l * 64 + o) * 64 + 2 * dp],
                       ff1_w[(l * 64 + o) * 64 + 2 * dp + 1]);
  } else if (idx < 16384) {
    int j = idx - 8192;
    int l = j >> 11, dhp = (j >> 6) & 31, o = j & 63;
    wpk2[j] = packh2(ff2_w[(l * 64 + o) * 64 + 2 * dhp],
                     ff2_w[(l * 64 + o) * 64 + 2 * dhp + 1]);
  }
}

// Butterfly stage on va (channels live in va[0..2m)), literal m.
#define BSTAGE(m)                                                    \
  do {                                                               \
    _Pragma("unroll") for (int k = 0; k < (m); k++) {                \
      bool up = (lane & (m)) != 0;                                   \
      float send = up ? va[k] : va[k + (m)];                         \
      float keep = up ? va[k + (m)] : va[k];                         \
      va[k] = keep + __shfl_xor(send, (m), 64);                      \
    }                                                                \
  } while (0)

__global__ __launch_bounds__(TPB, 2) void aat_kernel(
    const int* __restrict__ tokens, const float* __restrict__ emb,
    const float* __restrict__ lin_w, const float* __restrict__ lin_b,
    const float* __restrict__ ff1_b, const float* __restrict__ ff2_b,
    const float* __restrict__ n1_g, const float* __restrict__ n1_b,
    const float* __restrict__ n2_g, const float* __restrict__ n2_b,
    const float* __restrict__ out_w, const float* __restrict__ out_b,
    const uint32_t* __restrict__ wpk1, const uint32_t* __restrict__ wpk2,
    float* __restrict__ out) {
  __shared__ float red8[8][64];
  __shared__ float avgbuf[64];
  __shared__ __align__(8) float attnbuf[64];

  const int t = threadIdx.x;
  const int b = blockIdx.x;
  const int lane = t & 63;
  const int wv = t >> 6;

  u32v32 x0, x1;  // rows s=t and s=t+512, packed f16 pairs — SSA vectors

  // ---------------- embed * sqrt(d) + positional encoding ----------------
  auto embed_row = [&](int s, u32v32& xr) {
    int tok = tokens[b * 1000 + s];
    const float4* ev = (const float4*)(emb + (size_t)tok * 64);
    #pragma unroll
    for (int q = 0; q < 16; q++) {
      float4 v4 = ev[q];
      float xv[4] = {v4.x, v4.y, v4.z, v4.w};
      #pragma unroll
      for (int j = 0; j < 4; j++) {
        int d = 4 * q + j;
        // div_i = 10000^(-i/32); log2(10000)/32 = 0.41524101186
        float div = exp2f(-0.4152410118609203f * (float)(d >> 1));
        float ang = (float)s * div;
        float pe = (d & 1) ? cosf(ang) : sinf(ang);
        xv[j] = xv[j] * 8.0f + pe;
      }
      xr[2 * q] = packh2(xv[0], xv[1]);
      xr[2 * q + 1] = packh2(xv[2], xv[3]);
    }
  };
  embed_row(t, x0);
  if (t < 488) {
    embed_row(t + 512, x1);
  } else {
    #pragma unroll
    for (int dp = 0; dp < 32; dp++) x1[dp] = 0u;
  }

  for (int l = 0; l < NL; l++) {
    // ---------------- avg over sequence: butterfly reduce ----------------
    {
      f32v32 va, vb;  // channels 0..31 / 32..63
      #pragma unroll
      for (int dp = 0; dp < 32; dp++) {
        float2 a = unpackh2(x0[dp]);
        float s0 = a.x, s1 = a.y;
        if (t < 488) {
          float2 c = unpackh2(x1[dp]);
          s0 += c.x;
          s1 += c.y;
        }
        if (dp < 16) {
          va[2 * dp] = s0;
          va[2 * dp + 1] = s1;
        } else {
          vb[2 * dp - 32] = s0;
          vb[2 * dp - 31] = s1;
        }
      }
      // stage 32: fold vb into va
      #pragma unroll
      for (int k = 0; k < 32; k++) {
        bool up = (lane & 32) != 0;
        float send = up ? va[k] : vb[k];
        float keep = up ? vb[k] : va[k];
        va[k] = keep + __shfl_xor(send, 32, 64);
      }
      BSTAGE(16); BSTAGE(8); BSTAGE(4); BSTAGE(2); BSTAGE(1);
      __syncthreads();
      red8[wv][lane] = va[0];
    }
    __syncthreads();
    if (t < 64) {
      float s = 0.f;
      #pragma unroll
      for (int w = 0; w < 8; w++) s += red8[w][t];
      avgbuf[t] = s * 1e-3f;
    }
    __syncthreads();
    if (t < 64) {  // attn[o] = lin_b[o] + sum_d avg[d]*lin_w[o][d]
      const float* wr = lin_w + (size_t)(l * 64 + t) * 64;
      float a0 = lin_b[l * 64 + t], a1 = 0.f, a2 = 0.f, a3 = 0.f;
      #pragma unroll
      for (int d = 0; d < 64; d += 4) {
        a0 += avgbuf[d] * wr[d];
        a1 += avgbuf[d + 1] * wr[d + 1];
        a2 += avgbuf[d + 2] * wr[d + 2];
        a3 += avgbuf[d + 3] * wr[d + 3];
      }
      attnbuf[t] = (a0 + a1) + (a2 + a3);
    }
    __syncthreads();

    // ---------------- per-row: LN1 -> fused FF -> LN2 ----------------
    auto do_row = [&](u32v32& xr) {
      // LN1 stats over a = x + attn; keep a packed in xr
      float m0 = 0.f, m1 = 0.f, q0 = 0.f, q1 = 0.f;
      #pragma unroll
      for (int dp = 0; dp < 32; dp++) {
        float2 xv = unpackh2(xr[dp]);
        float2 at = ((const float2*)attnbuf)[dp];
        float a0 = xv.x + at.x, a1 = xv.y + at.y;
        m0 += a0;
        m1 += a1;
        q0 = fmaf(a0, a0, q0);
        q1 = fmaf(a1, a1, q1);
        xr[dp] = packh2(a0, a1);
      }
      float mu = (m0 + m1) * (1.0f / 64.0f);
      float var = (q0 + q1) * (1.0f / 64.0f) - mu * mu;
      float rs = rsqrtf(var + 1e-5f);
      #pragma unroll
      for (int dp = 0; dp < 32; dp++) {
        float2 av = unpackh2(xr[dp]);
        float y0 = fmaf((av.x - mu) * rs, n1_g[l * 64 + 2 * dp], n1_b[l * 64 + 2 * dp]);
        float y1 = fmaf((av.y - mu) * rs, n1_g[l * 64 + 2 * dp + 1], n1_b[l * 64 + 2 * dp + 1]);
        xr[dp] = packh2(y0, y1);  // y = LN1 out, residual for LN2
      }

      // fused mm1 -> relu -> mm2 partial accumulation (accE/accO = even/odd out ch)
      f32v32 accE, accO;
      #pragma unroll
      for (int dp = 0; dp < 32; dp++) {
        accE[dp] = ff2_b[l * 64 + 2 * dp];
        accO[dp] = ff2_b[l * 64 + 2 * dp + 1];
      }
      #pragma unroll 1
      for (int og = 0; og < 16; og++) {
        const uint32_t* wb1 = wpk1 + (size_t)(l * 64 + og * 4) * 32;
        float a0 = ff1_b[l * 64 + og * 4 + 0];
        float a1 = ff1_b[l * 64 + og * 4 + 1];
        float a2 = ff1_b[l * 64 + og * 4 + 2];
        float a3 = ff1_b[l * 64 + og * 4 + 3];
        #pragma unroll
        for (int dp = 0; dp < 32; dp++) {
          uint32_t y2 = xr[dp];
          a0 = fdot2h(y2, wb1[dp], a0);
          a1 = fdot2h(y2, wb1[32 + dp], a1);
          a2 = fdot2h(y2, wb1[64 + dp], a2);
          a3 = fdot2h(y2, wb1[96 + dp], a3);
        }
        uint32_t h01 = packh2(fmaxf(a0, 0.f), fmaxf(a1, 0.f));
        uint32_t h23 = packh2(fmaxf(a2, 0.f), fmaxf(a3, 0.f));
        const uint32_t* wb2 = wpk2 + (size_t)l * 2048 + (size_t)og * 128;
        #pragma unroll
        for (int dp = 0; dp < 32; dp++) {
          accE[dp] = fdot2h(h23, wb2[64 + 2 * dp], fdot2h(h01, wb2[2 * dp], accE[dp]));
          accO[dp] = fdot2h(h23, wb2[64 + 2 * dp + 1], fdot2h(h01, wb2[2 * dp + 1], accO[dp]));
        }
      }

      // residual + LN2
      float mm0 = 0.f, mm1v = 0.f, qq0 = 0.f, qq1 = 0.f;
      #pragma unroll
      for (int dp = 0; dp < 32; dp++) {
        float2 yv = unpackh2(xr[dp]);
        float t0 = accE[dp] + yv.x;
        float t1 = accO[dp] + yv.y;
        mm0 += t0;
        mm1v += t1;
        qq0 = fmaf(t0, t0, qq0);
        qq1 = fmaf(t1, t1, qq1);
        xr[dp] = packh2(t0, t1);
      }
      mu = (mm0 + mm1v) * (1.0f / 64.0f);
      var = (qq0 + qq1) * (1.0f / 64.0f) - mu * mu;
      rs = rsqrtf(var + 1e-5f);
      #pragma unroll
      for (int dp = 0; dp < 32; dp++) {
        float2 tv = unpackh2(xr[dp]);
        float v0 = fmaf((tv.x - mu) * rs, n2_g[l * 64 + 2 * dp], n2_b[l * 64 + 2 * dp]);
        float v1 = fmaf((tv.y - mu) * rs, n2_g[l * 64 + 2 * dp + 1], n2_b[l * 64 + 2 * dp + 1]);
        xr[dp] = packh2(v0, v1);
      }
    };
    do_row(x0);
    do_row(x1);  // rows >= 1000 compute garbage but are masked everywhere
  }

  // ---------------- output projection [B,S,2] ----------------
  auto emit_row = [&](int s, const u32v32& xr) {
    float a0 = out_b[0], a1 = out_b[1];
    #pragma unroll
    for (int dp = 0; dp < 32; dp++) {
      float2 xv = unpackh2(xr[dp]);
      a0 += xv.x * out_w[2 * dp] + xv.y * out_w[2 * dp + 1];
      a1 += xv.x * out_w[64 + 2 * dp] + xv.y * out_w[64 + 2 * dp + 1];
    }
    float2 res;
    res.x = a0;
    res.y = a1;
    *(float2*)(out + (size_t)(b * 1000 + s) * 2) = res;
  };
  emit_row(t, x0);
  if (t < 488) emit_row(t + 512, x1);
}

extern "C" void kernel_launch(void* const* d_in, const int* in_sizes, int n_in,
                              void* d_out, int out_size, void* d_ws, size_t ws_size,
                              hipStream_t stream) {
  const int* tokens = (const int*)d_in[0];
  const float* emb = (const float*)d_in[1];
  const float* lin_w = (const float*)d_in[2];
  const float* lin_b = (const float*)d_in[3];
  const float* ff1_w = (const float*)d_in[4];
  const float* ff1_b = (const float*)d_in[5];
  const float* ff2_w = (const float*)d_in[6];
  const float* ff2_b = (const float*)d_in[7];
  const float* n1_g = (const float*)d_in[8];
  const float* n1_b = (const float*)d_in[9];
  const float* n2_g = (const float*)d_in[10];
  const float* n2_b = (const float*)d_in[11];
  const float* out_w = (const float*)d_in[12];
  const float* out_b = (const float*)d_in[13];
  float* out = (float*)d_out;

  uint32_t* wpk1 = (uint32_t*)d_ws;       // 32 KiB
  uint32_t* wpk2 = wpk1 + 4 * 32 * 64;    // 32 KiB

  pack_weights_kernel<<<64, 256, 0, stream>>>(ff1_w, ff2_w, wpk1, wpk2);
  aat_kernel<<<512, TPB, 0, stream>>>(tokens, emb, lin_w, lin_b, ff1_b, ff2_b,
                                      n1_g, n1_b, n2_g, n2_b, out_w, out_b,
                                      wpk1, wpk2, out);
}